// Round 10
// baseline (215.588 us; speedup 1.0000x reference)
//
#include <hip/hip_runtime.h>

#define HH 512
#define WW 512
#define HW (HH*WW)
#define EPV 1e-20f

// Box window for center (y,x): rows y-3..y+4, cols x-3..x+4, zero-padded.
// f4 scheme (verified absmax 0.0039 in R9): 4 cols/lane, horizontal windows
// via prefix/suffix lane exchange, vertical via register rings (depth 8).
// R10: deep load FIFOs (prep 6-deep, main 3-deep) + smaller segs for 2x
// wave count — attack the exposed-latency regime R9's counters showed.

__device__ __forceinline__ float bpl(int addr, float v) {
    return __int_as_float(__builtin_amdgcn_ds_bpermute(addr, __float_as_int(v)));
}
__device__ __forceinline__ int rcl(int r) { return min(max(r, 0), HH - 1); }

// centered window (d=-3..+4) over strip cols u=4*lane+e
__device__ __forceinline__ float4 winC(float4 v, int aL1, int aR1) {
    float pre2 = v.x + v.y, pre3 = pre2 + v.z, g = pre3 + v.w;
    float suf2 = v.z + v.w, suf3 = v.y + suf2;
    float Ls1 = bpl(aL1, v.w), Ls2 = bpl(aL1, suf2), Ls3 = bpl(aL1, suf3);
    float Rp1 = bpl(aR1, v.x), Rp2 = bpl(aR1, pre2), Rp3 = bpl(aR1, pre3);
    float Rg  = bpl(aR1, g);
    return make_float4(Ls3 + g + Rp1, Ls2 + g + Rp2, Ls1 + g + Rp3, g + Rg);
}
// right-leaning window (d=1..8), serves output col x0+u
__device__ __forceinline__ float4 winR(float4 v, int aR1, int aR2) {
    float pre2 = v.x + v.y, pre3 = pre2 + v.z, g = pre3 + v.w;
    float suf2 = v.z + v.w, suf3 = v.y + suf2;
    float G1 = bpl(aR1, g);
    float P1 = bpl(aR2, v.x), P2 = bpl(aR2, pre2), P3 = bpl(aR2, pre3);
    float G2 = bpl(aR2, g);
    return make_float4(suf3 + G1 + P1, suf2 + G1 + P2, v.w + G1 + P3, G1 + G2);
}

// ---------------- prep: raw image -> centered (ac) + variance box (sii) ----
// One wave per (z, strip, 16-row seg). Strips x0 = {0,240,480}. 31 steps,
// 6-deep row FIFO.
__global__ __launch_bounds__(64) void prep_f4(
    const float* __restrict__ outs, const float* __restrict__ labs,
    float* __restrict__ ac, float* __restrict__ sii)
{
    const int l  = threadIdx.x;
    const int x0 = 240 * blockIdx.x;
    const int y0 = 16 * blockIdx.y;
    const int z  = blockIdx.z;

    const float* src = (z < 24) ? outs + z * HW : labs + (z - 24) * HW;
    float* acd = ac  + z * HW;
    float* sid = sii + z * HW;

    const int   bcol0 = x0 - 4 + 4 * l;
    const int   bcol  = min(max(bcol0, 0), WW - 4);
    const float cmask = (bcol0 >= 0 && bcol0 <= WW - 4) ? 1.f : 0.f;
    const int   ocol0 = x0 + 4 * l;
    const int   aL1 = ((l - 1) & 63) << 2;
    const int   aR1 = ((l + 1) & 63) << 2;
    const int   aR2 = ((l + 2) & 63) << 2;
    const bool  stA = (l >= 1 && l <= 60 && bcol0 >= 0 && bcol0 <= WW - 4);
    const bool  stS = (l >= ((x0 == 0) ? 0 : 1) && l <= 59 && ocol0 <= WW - 4);

    float4 fifo[6];
    #pragma unroll
    for (int k = 0; k < 6; ++k)
        fifo[k] = *(const float4*)&src[rcl(y0 - 7 + k) * WW + bcol];

    float4 araw[4], haR[8], hsR[8];
    float4 VA = make_float4(0,0,0,0), VS = make_float4(0,0,0,0);
    #pragma unroll
    for (int k = 0; k < 4; ++k) araw[k] = make_float4(0,0,0,0);
    #pragma unroll
    for (int k = 0; k < 8; ++k) { haR[k] = make_float4(0,0,0,0); hsR[k] = make_float4(0,0,0,0); }

    #pragma unroll
    for (int t = 0; t < 31; ++t) {
        const int   k  = t & 7;
        const int   r  = y0 - 7 + t;
        const float rm = (r >= 0 && r < HH) ? cmask : 0.f;
        float4 raw = fifo[t % 6];
        float4 av  = make_float4(raw.x*rm, raw.y*rm, raw.z*rm, raw.w*rm);
        if (t <= 24) fifo[t % 6] = *(const float4*)&src[rcl(r + 6) * WW + bcol];

        float4 h = winC(av, aL1, aR1);
        VA.x += h.x - haR[k].x; VA.y += h.y - haR[k].y;
        VA.z += h.z - haR[k].z; VA.w += h.w - haR[k].w;
        haR[k] = h;

        float4 aold = araw[t & 3]; araw[t & 3] = av;   // row c = r-4
        const int   c  = r - 4;
        const float cm = (c >= 0 && c < HH) ? cmask : 0.f;
        float4 acv = make_float4((aold.x - VA.x*(1.f/64.f))*cm,
                                 (aold.y - VA.y*(1.f/64.f))*cm,
                                 (aold.z - VA.z*(1.f/64.f))*cm,
                                 (aold.w - VA.w*(1.f/64.f))*cm);
        if (t >= 11 && t <= 26) {
            if (stA) *(float4*)&acd[c * WW + bcol0] = acv;
        }
        float4 sq = make_float4(acv.x*acv.x, acv.y*acv.y, acv.z*acv.z, acv.w*acv.w);
        float4 h2 = winR(sq, aR1, aR2);
        VS.x += h2.x - hsR[k].x; VS.y += h2.y - hsR[k].y;
        VS.z += h2.z - hsR[k].z; VS.w += h2.w - hsR[k].w;
        hsR[k] = h2;
        if (t >= 15) {
            const int y = c - 4;                        // y in [y0, y0+15]
            if (stS) *(float4*)&sid[y * WW + ocol0] =
                make_float4(fmaxf(VS.x, EPV), fmaxf(VS.y, EPV),
                            fmaxf(VS.z, EPV), fmaxf(VS.w, EPV));
        }
    }
}

// ---------------- main: product boxes, all 4 j per wave --------------------
// One wave per (z=b*6+i, strip x0={0,240,480}, 8-row seg). 15 steps,
// 3-deep fa/fb FIFO, 1-step psi/psj lookahead.
__global__ __launch_bounds__(64, 2) void ncc_f4(
    const float* __restrict__ ac, const float* __restrict__ sii,
    float* __restrict__ out)
{
    const int l  = threadIdx.x;
    const int x0 = 240 * blockIdx.x;
    const int y0 = 8 * blockIdx.y;
    const int z  = blockIdx.z;               // b*6 + i
    const int b  = z / 6;

    const float* acp = ac + z * HW;
    const float* sip = sii + z * HW;
    const float* bcp[4]; const float* sjp[4];
    #pragma unroll
    for (int j = 0; j < 4; ++j) {
        bcp[j] = ac  + (24 + b * 4 + j) * HW;
        sjp[j] = sii + (24 + b * 4 + j) * HW;
    }

    const int   bcol0 = x0 - 4 + 4 * l;
    const int   bcol  = min(max(bcol0, 0), WW - 4);
    const float cmask = (bcol0 >= 0 && bcol0 <= WW - 4) ? 1.f : 0.f;
    const int   ocol0 = x0 + 4 * l;
    const int   ocol  = min(ocol0, WW - 4);
    const float om    = (l <= 59 && ocol0 <= WW - 4) ? 1.f : 0.f;
    const int   aR1 = ((l + 1) & 63) << 2;
    const int   aR2 = ((l + 2) & 63) << 2;

    // 3-deep FIFO on a and b rows: slot t%3 holds product row c(t)=y0-3+t
    float4 fa[3], fb[4][3];
    #pragma unroll
    for (int k = 0; k < 3; ++k) {
        const int rk = rcl(y0 - 3 + k) * WW + bcol;
        fa[k] = *(const float4*)&acp[rk];
        #pragma unroll
        for (int j = 0; j < 4; ++j) fb[j][k] = *(const float4*)&bcp[j][rk];
    }

    float4 ring[4][8], VS[4];
    #pragma unroll
    for (int j = 0; j < 4; ++j) {
        VS[j] = make_float4(0,0,0,0);
        #pragma unroll
        for (int k = 0; k < 8; ++k) ring[j][k] = make_float4(0,0,0,0);
    }
    float4 xs = make_float4(0,0,0,0);
    float4 psi = make_float4(0,0,0,0), psj[4];
    #pragma unroll
    for (int j = 0; j < 4; ++j) psj[j] = make_float4(0,0,0,0);

    #pragma unroll
    for (int t = 0; t < 15; ++t) {
        const int   k  = t & 7;
        const int   c  = y0 - 3 + t;
        const float rm = (c >= 0 && c < HH) ? cmask : 0.f;
        float4 av = fa[t % 3];
        av = make_float4(av.x*rm, av.y*rm, av.z*rm, av.w*rm);
        float4 bv0 = fb[0][t % 3], bv1 = fb[1][t % 3];
        float4 bv2 = fb[2][t % 3], bv3 = fb[3][t % 3];
        if (t <= 11) {                       // refill row c+3, used at t+3
            const int rn = rcl(c + 3) * WW + bcol;
            fa[t % 3] = *(const float4*)&acp[rn];
            #pragma unroll
            for (int j = 0; j < 4; ++j)
                fb[j][t % 3] = *(const float4*)&bcp[j][rn];
        }
        if (t >= 6 && t <= 13) {             // prefetch emit row y(t+1)=y0+t-6
            const int yn = (y0 + t - 6) * WW + ocol;
            psi = *(const float4*)&sip[yn];
            #pragma unroll
            for (int j = 0; j < 4; ++j)
                psj[j] = *(const float4*)&sjp[j][yn];
        }
        float4 h;
        h = winR(make_float4(av.x*bv0.x, av.y*bv0.y, av.z*bv0.z, av.w*bv0.w), aR1, aR2);
        VS[0].x += h.x - ring[0][k].x; VS[0].y += h.y - ring[0][k].y;
        VS[0].z += h.z - ring[0][k].z; VS[0].w += h.w - ring[0][k].w; ring[0][k] = h;
        h = winR(make_float4(av.x*bv1.x, av.y*bv1.y, av.z*bv1.z, av.w*bv1.w), aR1, aR2);
        VS[1].x += h.x - ring[1][k].x; VS[1].y += h.y - ring[1][k].y;
        VS[1].z += h.z - ring[1][k].z; VS[1].w += h.w - ring[1][k].w; ring[1][k] = h;
        h = winR(make_float4(av.x*bv2.x, av.y*bv2.y, av.z*bv2.z, av.w*bv2.w), aR1, aR2);
        VS[2].x += h.x - ring[2][k].x; VS[2].y += h.y - ring[2][k].y;
        VS[2].z += h.z - ring[2][k].z; VS[2].w += h.w - ring[2][k].w; ring[2][k] = h;
        h = winR(make_float4(av.x*bv3.x, av.y*bv3.y, av.z*bv3.z, av.w*bv3.w), aR1, aR2);
        VS[3].x += h.x - ring[3][k].x; VS[3].y += h.y - ring[3][k].y;
        VS[3].z += h.z - ring[3][k].z; VS[3].w += h.w - ring[3][k].w; ring[3][k] = h;

        if (t >= 7) {
            float4 si = psi;
            float mmx = -1.f, mmy = -1.f, mmz = -1.f, mmw = -1.f;
            #pragma unroll
            for (int j = 0; j < 4; ++j) {
                float4 sj = psj[j];
                mmx = fmaxf(mmx, VS[j].x * __frsqrt_rn(fmaxf(si.x * sj.x, 1e-37f)));
                mmy = fmaxf(mmy, VS[j].y * __frsqrt_rn(fmaxf(si.y * sj.y, 1e-37f)));
                mmz = fmaxf(mmz, VS[j].z * __frsqrt_rn(fmaxf(si.z * sj.z, 1e-37f)));
                mmw = fmaxf(mmw, VS[j].w * __frsqrt_rn(fmaxf(si.w * sj.w, 1e-37f)));
            }
            xs.x += om * (1.f - fminf(mmx, 1.f));
            xs.y += om * (1.f - fminf(mmy, 1.f));
            xs.z += om * (1.f - fminf(mmz, 1.f));
            xs.w += om * (1.f - fminf(mmw, 1.f));
        }
    }

    float xt = xs.x + xs.y + xs.z + xs.w;
    #pragma unroll
    for (int off = 32; off > 0; off >>= 1) xt += __shfl_down(xt, off);
    if (l == 0) {
        atomicAdd(&out[1 + z], xt * (1.f / (float)HW));
        atomicAdd(&out[0],     xt * (1.f / (24.f * (float)HW)));
    }
}

extern "C" void kernel_launch(void* const* d_in, const int* in_sizes, int n_in,
                              void* d_out, int out_size, void* d_ws, size_t ws_size,
                              hipStream_t stream) {
    const float* outs = (const float*)d_in[0];   // (4,6,512,512)
    const float* labs = (const float*)d_in[1];   // (4,4,512,512)
    float* out = (float*)d_out;                  // 25 floats
    float* ws  = (float*)d_ws;

    float* acw  = ws;                 // 40*HW (a:0..23, b:24..39)
    float* siiw = ws + 40 * HW;       // 40*HW

    hipMemsetAsync(d_out, 0, out_size * sizeof(float), stream);

    // prep: 3 strips x 32 segs(16 rows) x 40 images = 3840 waves
    prep_f4<<<dim3(3, 32, 40), 64, 0, stream>>>(outs, labs, acw, siiw);
    // main: 3 strips x 64 segs(8 rows) x 24 (b,i) = 4608 waves
    ncc_f4<<<dim3(3, 64, 24), 64, 0, stream>>>(acw, siiw, out);
}